// Round 1
// 278.816 us; speedup vs baseline: 1.0310x; 1.0310x over previous
//
#include <hip/hip_runtime.h>
#include <math.h>

typedef __attribute__((ext_vector_type(8)))  short bf16x8;   // 8 bf16 = 4 VGPR
typedef __attribute__((ext_vector_type(16))) float f32x16;   // 32x32 MFMA acc
typedef __attribute__((ext_vector_type(4)))  unsigned uint4v;

#define MFMA32(a, b, c) __builtin_amdgcn_mfma_f32_32x32x16_bf16((a), (b), (c), 0, 0, 0)

namespace {
constexpr int HWF   = 256;
constexpr int MEMD  = 1024;
constexpr int NROWS = 65536;
constexpr int TM    = 256;          // token rows per block: 8 waves x 32 rows
constexpr int NT    = MEMD / 64;    // 16 j-tiles of 64
constexpr int THREADS = 512;
constexpr float C1v  = 0.01f;
constexpr float C2v  = 0.03f;
constexpr float EPSv = 1e-8f;
constexpr float RK   = 1.0f / 255.0f;

// LDS map (bytes): K dbuf | V dbuf | stats dbuf | l-redistribute
constexpr int KB0 = 0;              // 32 KB K tile (64 rows x 512B, xor-swizzled)
constexpr int KB1 = 32768;
constexpr int VB0 = 65536;          // 32 KB V tile (256 rows x 128B, xor-swizzled)
constexpr int VB1 = 98304;
constexpr int SB0 = 131072;         // 1 KB stats tile (64 x float4{2km, km^2+C1, kv+C2, 0})
constexpr int SB1 = 132096;
constexpr int LRED = 133120;        // 8 waves x 32 x f32
constexpr int SMEM_SZ = LRED + 1024;   // 134144 < 160 KiB
}

__device__ __forceinline__ short f2bf(float f) {            // RNE float->bf16
    union { float f; unsigned u; } v; v.f = f;
    unsigned r = v.u + 0x7fffu + ((v.u >> 16) & 1u);
    return (short)(r >> 16);
}

// packed f32 pair -> 2 bf16 in one u32 (src0 -> [15:0], src1 -> [31:16])
__device__ __forceinline__ unsigned cvtpk(float a, float b) {
    unsigned r;
    asm("v_cvt_pk_bf16_f32 %0, %1, %2" : "=v"(r) : "v"(a), "v"(b));
    return r;
}

// v_permlane32_swap_b32: a.lanes[32..63] <-> b.lanes[0..31].
// After: a = {a.lo32, b.lo32}, b = {a.hi32, b.hi32}.
__device__ __forceinline__ void plswap(unsigned &a, unsigned &b) {
#if defined(__has_builtin) && __has_builtin(__builtin_amdgcn_permlane32_swap)
    auto r = __builtin_amdgcn_permlane32_swap((int)a, (int)b, false, false);
    a = (unsigned)r[0]; b = (unsigned)r[1];
#else
    const bool h = (threadIdx.x & 32) != 0;
    const unsigned ax = (unsigned)__shfl_xor((int)a, 32);
    const unsigned bx = (unsigned)__shfl_xor((int)b, 32);
    const unsigned na = h ? bx : a;
    const unsigned nb = h ? b : ax;
    a = na; b = nb;
#endif
}

// async global->LDS DMA: 32 KB tile, wave w copies bytes [w*4096, w*4096+4096)
__device__ __forceinline__ void dma_tile(const short* gbase, char* smem, int ldsbase,
                                         int wave, int lane) {
    const char* g = (const char*)gbase + wave * 4096 + lane * 16;
    char* l = smem + ldsbase + wave * 4096;
    #pragma unroll
    for (int i = 0; i < 4; ++i) {
        __builtin_amdgcn_global_load_lds(
            (const __attribute__((address_space(1))) unsigned int*)(g + i * 1024),
            (__attribute__((address_space(3))) unsigned int*)(l + i * 1024), 16, 0, 0);
    }
}

// 1 KB stats tile: 64 x float4, one wave, one instr
__device__ __forceinline__ void dma_stats(const float* sblob, char* smem, int sb,
                                          int jt, int lane) {
    __builtin_amdgcn_global_load_lds(
        (const __attribute__((address_space(1))) unsigned int*)
            ((const char*)sblob + (size_t)jt * 1024 + lane * 16),
        (__attribute__((address_space(3))) unsigned int*)(smem + sb + lane * 16), 16, 0, 0);
}

// ---------------------------------------------------------------------------
// Wq -> bf16 (65536 elems)
// ---------------------------------------------------------------------------
__global__ __launch_bounds__(256) void cast_wq(const float* __restrict__ W,
                                               short* __restrict__ Wb) {
    int i = blockIdx.x * 256 + threadIdx.x;
    Wb[i] = f2bf(W[i]);
}

// ---------------------------------------------------------------------------
// prep: per block 4 memory slots. kc (centered k) -> swizzled K blob,
// v^T -> swizzled V blob, per-j ssim constants -> sblob float4.
// Blob tile format == exact LDS image consumed by attn (DMA-able).
// ---------------------------------------------------------------------------
__global__ __launch_bounds__(256) void prep_kv(
    const float* __restrict__ mem, const float* __restrict__ Wk,
    const float* __restrict__ Wv, short* __restrict__ kblob,
    short* __restrict__ vblob, float4* __restrict__ sblob)
{
    __shared__ __align__(16) float mrows[4][HWF];
    __shared__ float redS[4][8];
    const int t = threadIdx.x, j0 = blockIdx.x * 4;

    for (int r = 0; r < 4; ++r) mrows[r][t] = mem[(size_t)(j0 + r) * HWF + t];
    __syncthreads();

    const float4* wk4 = reinterpret_cast<const float4*>(Wk + (size_t)t * HWF);
    const float4* wv4 = reinterpret_cast<const float4*>(Wv + (size_t)t * HWF);
    float kt[4] = {0, 0, 0, 0}, vt[4] = {0, 0, 0, 0};
    for (int i = 0; i < 64; ++i) {
        const float4 a = wk4[i], b = wv4[i];
        for (int r = 0; r < 4; ++r) {
            const float4 m = reinterpret_cast<const float4*>(mrows[r])[i];
            kt[r] += m.x * a.x + m.y * a.y + m.z * a.z + m.w * a.w;
            vt[r] += m.x * b.x + m.y * b.y + m.z * b.z + m.w * b.w;
        }
    }

    const int wv_ = t >> 6, ln = t & 63;
    {   // mean partials
        float s[4];
        for (int r = 0; r < 4; ++r) s[r] = kt[r];
        for (int m = 1; m < 64; m <<= 1)
            for (int r = 0; r < 4; ++r) s[r] += __shfl_xor(s[r], m);
        if (ln == 0) {
            for (int r = 0; r < 4; ++r) redS[wv_][r] = s[r];
        }
    }
    __syncthreads();
    float kmv[4], kc4[4];
    for (int r = 0; r < 4; ++r) {
        kmv[r] = (redS[0][r] + redS[1][r] + redS[2][r] + redS[3][r]) * (1.f / HWF);
        kc4[r] = kt[r] - kmv[r];
    }
    {   // var partials
        float s[4];
        for (int r = 0; r < 4; ++r) s[r] = kc4[r] * kc4[r];
        for (int m = 1; m < 64; m <<= 1)
            for (int r = 0; r < 4; ++r) s[r] += __shfl_xor(s[r], m);
        if (ln == 0) {
            for (int r = 0; r < 4; ++r) redS[wv_][4 + r] = s[r];
        }
    }
    __syncthreads();
    float kvv[4];
    for (int r = 0; r < 4; ++r)
        kvv[r] = (redS[0][4+r] + redS[1][4+r] + redS[2][4+r] + redS[3][4+r]) * (1.f / (HWF - 1));

    const int jt = j0 >> 6;
    for (int r = 0; r < 4; ++r) {
        const int ro = (j0 & 63) + r;
        // K blob: [jt][row ro (j)][512B: chunk^(ro&7)][8 bf16]
        kblob[jt * 16384 + ro * 256 + (((t >> 3) ^ (ro & 7)) * 8) + (t & 7)] = f2bf(kc4[r]);
        // V blob: [jt][row c=t (feature)][128B: chunk^(c&7)][8 bf16 over j]
        vblob[jt * 16384 + t * 64 + (((ro >> 3) ^ (t & 7)) * 8) + (ro & 7)] = f2bf(vt[r]);
    }
    if (t < 4) {
        sblob[j0 + t] = make_float4(2.f * kmv[t], kmv[t] * kmv[t] + C1v,
                                    kvv[t] + C2v, 0.f);
    }
}

// ---------------------------------------------------------------------------
// attn: TM=256 rows/block, 8 waves, wave rg owns 32 token rows x all j x all c.
// Swapped-operand MFMA chain keeps P in registers:
//   prologue  qD = MFMA(Wq, x)  -> lane=token; cvt_pk+permlane32_swap -> qA frags
//   QK        S  = MFMA(K, qA)  -> lane=token, regs=j; ssim+exp in-register
//   pack      cvt_pk pairs + permlane32_swap -> PV A-frags (no P LDS, no barrier)
//   PV        O += MFMA(P, V) over 8 col-tiles; l = f32 per-lane accumulator
// One __syncthreads per j-tile (DMA drain); K/V/stats double-buffered DMA.
// MFMA 32x32x16 layouts (HW-verified m74/m101):
//   A[m=lane&31][k=8*(lane>>5)+e], B[k=8*(lane>>5)+e][n=lane&31],
//   D col=lane&31, row=(reg&3)+8*(reg>>2)+4*(lane>>5).
// ---------------------------------------------------------------------------
__global__ __launch_bounds__(THREADS, 2) void attn(
    const float* __restrict__ x, const short* __restrict__ wq_bf,
    const short* __restrict__ kblob, const short* __restrict__ vblob,
    const float* __restrict__ sblob, float* __restrict__ out)
{
    __shared__ __align__(16) char smem[SMEM_SZ];
    const int t = threadIdx.x, wave = t >> 6, lane = t & 63;
    const int lo = lane & 31, hi = lane >> 5;
    const int rg = wave;                    // 8 row-groups of 32 tokens
    const int n0 = blockIdx.x * TM;
    const int tok = n0 + 32 * rg + lo;      // this lane's token row

    // ---- DMA tile 0 immediately (overlaps whole prologue) ----
    dma_tile(kblob, smem, KB0, wave, lane);
    dma_tile(vblob, smem, VB0, wave, lane);
    if (wave == 0) dma_stats(sblob, smem, SB0, 0, lane);

    // ---- x B-frags: lane = token (n index), regs = feature ----
    bf16x8 xB[16];
    {
        const float* xr = x + (size_t)tok * HWF;
        #pragma unroll
        for (int s = 0; s < 16; ++s) {
            const float4 a = *reinterpret_cast<const float4*>(xr + 16 * s + 8 * hi);
            const float4 b = *reinterpret_cast<const float4*>(xr + 16 * s + 8 * hi + 4);
            uint4v u;
            u[0] = cvtpk(a.x, a.y); u[1] = cvtpk(a.z, a.w);
            u[2] = cvtpk(b.x, b.y); u[3] = cvtpk(b.z, b.w);
            xB[s] = __builtin_bit_cast(bf16x8, u);
        }
    }

    // ---- q = Wq @ x^T (swapped): D col = token, row = out-feature ----
    f32x16 qD[8];
    #pragma unroll
    for (int nt = 0; nt < 8; ++nt) qD[nt] = (f32x16)(0.f);
    #pragma unroll
    for (int nt = 0; nt < 8; ++nt) {
        #pragma unroll
        for (int s = 0; s < 16; ++s) {
            const bf16x8 wa = *reinterpret_cast<const bf16x8*>(
                wq_bf + (size_t)(32 * nt + lo) * HWF + 16 * s + 8 * hi);
            qD[nt] = MFMA32(wa, xB[s], qD[nt]);
        }
    }

    // ---- per-token stats fully in-lane (own half + partner half) ----
    float qs = 0.f, qss = 0.f;
    #pragma unroll
    for (int nt = 0; nt < 8; ++nt)
        #pragma unroll
        for (int i = 0; i < 16; ++i) {
            const float v = qD[nt][i];
            qs += v; qss = __builtin_fmaf(v, v, qss);
        }
    qs += __shfl_xor(qs, 32);
    qss += __shfl_xor(qss, 32);
    const float qm  = qs * (1.f / HWF);
    const float qv  = (qss - qs * qs * (1.f / HWF)) * (1.f / (HWF - 1));
    const float qm2 = qm * qm;

    // ---- qA frags in-register: cvt_pk pairs + permlane32_swap ----
    bf16x8 qA[16];
    #pragma unroll
    for (int nt = 0; nt < 8; ++nt) {
        unsigned w[8];
        #pragma unroll
        for (int p = 0; p < 8; ++p) w[p] = cvtpk(qD[nt][2 * p], qD[nt][2 * p + 1]);
        #pragma unroll
        for (int h = 0; h < 2; ++h) {
            unsigned a0 = w[4 * h + 0], b0 = w[4 * h + 2];
            unsigned a1 = w[4 * h + 1], b1 = w[4 * h + 3];
            plswap(a0, b0); plswap(a1, b1);
            uint4v u; u[0] = a0; u[1] = a1; u[2] = b0; u[3] = b1;
            qA[2 * nt + h] = __builtin_bit_cast(bf16x8, u);
        }
    }

    // ---- main loop over 16 j-tiles ----
    f32x16 O4[8];
    #pragma unroll
    for (int ct = 0; ct < 8; ++ct) O4[ct] = (f32x16)(0.f);
    float l = 0.f;
    const int rx = (lo & 7);                // xor swizzle nibble (row&7 == c&7 == lo&7)

    for (int jt = 0; jt < NT; ++jt) {
        const int cur = jt & 1;
        const int kb = cur ? KB1 : KB0, vb = cur ? VB1 : VB0, sb = cur ? SB1 : SB0;
        const int kbn = cur ? KB0 : KB1, vbn = cur ? VB0 : VB1, sbn = cur ? SB0 : SB1;
        __syncthreads();                    // drains DMA(jt); prev tile reads done
        if (jt + 1 < NT) {                  // prefetch stays in flight across compute
            dma_tile(kblob + (size_t)(jt + 1) * 16384, smem, kbn, wave, lane);
            dma_tile(vblob + (size_t)(jt + 1) * 16384, smem, vbn, wave, lane);
            if (wave == 0) dma_stats(sblob, smem, sbn, jt + 1, lane);
        }

        #pragma unroll
        for (int jh = 0; jh < 2; ++jh) {
            // ---- S = K @ q^T : lane = token, regs = j-offset ----
            f32x16 sacc = (f32x16)(0.f);
            __builtin_amdgcn_s_setprio(1);
            #pragma unroll
            for (int s = 0; s < 16; ++s) {
                const bf16x8 kfr = *reinterpret_cast<const bf16x8*>(
                    smem + kb + jh * 16384 + lo * 512 + (((2 * s + hi) ^ rx) * 16));
                sacc = MFMA32(kfr, qA[s], sacc);
            }
            __builtin_amdgcn_s_setprio(0);

            // ---- ssim -> p -> packed bf16 pairs (all in registers) ----
            unsigned pw[8];
            #pragma unroll
            for (int p = 0; p < 8; ++p) {
                float pr[2];
                #pragma unroll
                for (int q = 0; q < 2; ++q) {
                    const int i = 2 * p + q;
                    const float4 st = *reinterpret_cast<const float4*>(
                        smem + sb + hi * 64 + ((32 * jh + (i & 3) + 8 * (i >> 2)) * 16));
                    const float cov2 = __builtin_fmaf(sacc[i], 2.f * RK, C2v);
                    const float num  = __builtin_fmaf(st.x, qm, C1v) * cov2;
                    const float den  = __builtin_fmaf(qm2 + st.y, qv + st.z, EPSv);
                    pr[q] = __expf(__fdividef(num, den));
                    l += pr[q];
                }
                pw[p] = cvtpk(pr[0], pr[1]);
            }

            // ---- O += P @ V : A-frags via permlane32_swap, B from LDS ----
            #pragma unroll
            for (int h = 0; h < 2; ++h) {
                const int ks = 2 * jh + h;
                unsigned a0 = pw[4 * h + 0], b0 = pw[4 * h + 2];
                unsigned a1 = pw[4 * h + 1], b1 = pw[4 * h + 3];
                plswap(a0, b0); plswap(a1, b1);
                uint4v u; u[0] = a0; u[1] = a1; u[2] = b0; u[3] = b1;
                const bf16x8 pa = __builtin_bit_cast(bf16x8, u);
                __builtin_amdgcn_s_setprio(1);
                #pragma unroll
                for (int ct = 0; ct < 8; ++ct) {
                    const bf16x8 vfr = *reinterpret_cast<const bf16x8*>(
                        smem + vb + (32 * ct + lo) * 128 + (((2 * ks + hi) ^ rx) * 16));
                    O4[ct] = MFMA32(pa, vfr, O4[ct]);
                }
                __builtin_amdgcn_s_setprio(0);
            }
        }
    }

    // ---- l: lane-sum -> per-row via tiny wave-local LDS redistribute ----
    const float lf = l + __shfl_xor(l, 32);
    if (hi == 0)
        *reinterpret_cast<float*>(smem + LRED + (wave * 32 + lo) * 4) = lf;
    // same-wave DS ops complete in order; reads below see the writes
    float rl[16];
    #pragma unroll
    for (int g = 0; g < 4; ++g) {
        const float4 lv = *reinterpret_cast<const float4*>(
            smem + LRED + wave * 128 + (8 * g + 4 * hi) * 4);
        rl[4 * g + 0] = 1.f / lv.x;
        rl[4 * g + 1] = 1.f / lv.y;
        rl[4 * g + 2] = 1.f / lv.z;
        rl[4 * g + 3] = 1.f / lv.w;
    }

    #pragma unroll
    for (int ct = 0; ct < 8; ++ct) {
        #pragma unroll
        for (int i = 0; i < 16; ++i) {
            const int row = 32 * rg + (i & 3) + 8 * (i >> 2) + 4 * hi;
            out[(size_t)(n0 + row) * HWF + 32 * ct + lo] = O4[ct][i] * rl[i];
        }
    }
}

extern "C" void kernel_launch(void* const* d_in, const int* in_sizes, int n_in,
                              void* d_out, int out_size, void* d_ws, size_t ws_size,
                              hipStream_t stream) {
    (void)in_sizes; (void)n_in; (void)out_size; (void)ws_size;
    const float* x   = (const float*)d_in[0];
    const float* mem = (const float*)d_in[1];
    const float* Wq  = (const float*)d_in[2];
    const float* Wk  = (const float*)d_in[3];
    const float* Wv  = (const float*)d_in[4];
    float* out = (float*)d_out;

    // workspace (~1.2 MB): wq_bf | kblob | vblob | sblob
    short* wq_bf = (short*)d_ws;                        // 65536
    short* kblob = wq_bf + 65536;                       // 262144 (16 tiles x 16384)
    short* vblob = kblob + (size_t)MEMD * HWF;          // 262144
    float4* sblob = (float4*)(vblob + (size_t)MEMD * HWF);  // 1024 x 16B

    cast_wq<<<256, 256, 0, stream>>>(Wq, wq_bf);
    prep_kv<<<MEMD / 4, 256, 0, stream>>>(mem, Wk, Wv, kblob, vblob, sblob);
    attn<<<NROWS / TM, THREADS, 0, stream>>>(x, wq_bf, kblob, vblob,
                                             (const float*)sblob, out);
}

// Round 2
// 259.095 us; speedup vs baseline: 1.1095x; 1.0761x over previous
//
#include <hip/hip_runtime.h>
#include <math.h>

typedef __attribute__((ext_vector_type(8)))  short bf16x8;   // 8 bf16 = 4 VGPR
typedef __attribute__((ext_vector_type(16))) float f32x16;   // 32x32 MFMA acc
typedef __attribute__((ext_vector_type(4)))  float f32x4;
typedef __attribute__((ext_vector_type(4)))  unsigned uint4v;

#define MFMA32(a, b, c) __builtin_amdgcn_mfma_f32_32x32x16_bf16((a), (b), (c), 0, 0, 0)

namespace {
constexpr int HWF   = 256;
constexpr int MEMD  = 1024;
constexpr int NROWS = 65536;
constexpr int TM    = 128;          // token rows per block: 4 waves x 32 rows
constexpr int NT    = MEMD / 32;    // 32 j-tiles of 32
constexpr int THREADS = 256;        // 4 waves -> 2 blocks/CU (LDS 78 KB, regs 256/wave)
constexpr float C1v  = 0.01f;
constexpr float C2v  = 0.03f;
constexpr float EPSv = 1e-8f;
constexpr float RK   = 1.0f / 255.0f;

// LDS map (bytes): K dbuf | V dbuf | stats (one-shot SoA) | l-redistribute
constexpr int KB0 = 0;              // 16 KB K tile (32 rows x 512B, xor-swizzled)
constexpr int KB1 = 16384;
constexpr int VB0 = 32768;          // 16 KB V tile (256 rows x 64B, xor-swizzled)
constexpr int VB1 = 49152;
constexpr int STATS = 65536;        // 12 KB: sa[1024] | sb[1024] | sc[1024]
constexpr int LRED  = STATS + 12288;  // 4 waves x 32 x f32 = 512 B
constexpr int SMEM_SZ = LRED + 512;   // 78336 B -> 2 blocks/CU (156672 < 160 KiB)
}

__device__ __forceinline__ short f2bf(float f) {            // RNE float->bf16
    union { float f; unsigned u; } v; v.f = f;
    unsigned r = v.u + 0x7fffu + ((v.u >> 16) & 1u);
    return (short)(r >> 16);
}

// packed f32 pair -> 2 bf16 in one u32 (src0 -> [15:0], src1 -> [31:16])
__device__ __forceinline__ unsigned cvtpk(float a, float b) {
    unsigned r;
    asm("v_cvt_pk_bf16_f32 %0, %1, %2" : "=v"(r) : "v"(a), "v"(b));
    return r;
}

// v_permlane32_swap_b32: a.lanes[32..63] <-> b.lanes[0..31].
__device__ __forceinline__ void plswap(unsigned &a, unsigned &b) {
#if defined(__has_builtin) && __has_builtin(__builtin_amdgcn_permlane32_swap)
    auto r = __builtin_amdgcn_permlane32_swap((int)a, (int)b, false, false);
    a = (unsigned)r[0]; b = (unsigned)r[1];
#else
    const bool h = (threadIdx.x & 32) != 0;
    const unsigned ax = (unsigned)__shfl_xor((int)a, 32);
    const unsigned bx = (unsigned)__shfl_xor((int)b, 32);
    const unsigned na = h ? bx : a;
    const unsigned nb = h ? b : ax;
    a = na; b = nb;
#endif
}

// async global->LDS DMA: 16 KB tile, wave w (of 4) copies [w*4096, w*4096+4096)
__device__ __forceinline__ void dma_tile16(const short* gbase, char* smem, int ldsbase,
                                           int wave, int lane) {
    const char* g = (const char*)gbase + wave * 4096 + lane * 16;
    char* l = smem + ldsbase + wave * 4096;
    #pragma unroll
    for (int i = 0; i < 4; ++i) {
        __builtin_amdgcn_global_load_lds(
            (const __attribute__((address_space(1))) unsigned int*)(g + i * 1024),
            (__attribute__((address_space(3))) unsigned int*)(l + i * 1024), 16, 0, 0);
    }
}

// ---------------------------------------------------------------------------
// Wq -> bf16 (65536 elems)
// ---------------------------------------------------------------------------
__global__ __launch_bounds__(256) void cast_wq(const float* __restrict__ W,
                                               short* __restrict__ Wb) {
    int i = blockIdx.x * 256 + threadIdx.x;
    Wb[i] = f2bf(W[i]);
}

// ---------------------------------------------------------------------------
// prep: per block 4 memory slots. kc (centered k) -> swizzled K blob (32-j
// tiles), v^T -> swizzled V blob (32-j tiles), ssim constants -> SoA stats.
// Blob tile format == exact LDS image consumed by attn (DMA-able).
// ---------------------------------------------------------------------------
__global__ __launch_bounds__(256) void prep_kv(
    const float* __restrict__ mem, const float* __restrict__ Wk,
    const float* __restrict__ Wv, short* __restrict__ kblob,
    short* __restrict__ vblob, float* __restrict__ sblob)
{
    __shared__ __align__(16) float mrows[4][HWF];
    __shared__ float redS[4][8];
    const int t = threadIdx.x, j0 = blockIdx.x * 4;

    for (int r = 0; r < 4; ++r) mrows[r][t] = mem[(size_t)(j0 + r) * HWF + t];
    __syncthreads();

    const float4* wk4 = reinterpret_cast<const float4*>(Wk + (size_t)t * HWF);
    const float4* wv4 = reinterpret_cast<const float4*>(Wv + (size_t)t * HWF);
    float kt[4] = {0, 0, 0, 0}, vt[4] = {0, 0, 0, 0};
    for (int i = 0; i < 64; ++i) {
        const float4 a = wk4[i], b = wv4[i];
        for (int r = 0; r < 4; ++r) {
            const float4 m = reinterpret_cast<const float4*>(mrows[r])[i];
            kt[r] += m.x * a.x + m.y * a.y + m.z * a.z + m.w * a.w;
            vt[r] += m.x * b.x + m.y * b.y + m.z * b.z + m.w * b.w;
        }
    }

    const int wv_ = t >> 6, ln = t & 63;
    {   // mean partials
        float s[4];
        for (int r = 0; r < 4; ++r) s[r] = kt[r];
        for (int m = 1; m < 64; m <<= 1)
            for (int r = 0; r < 4; ++r) s[r] += __shfl_xor(s[r], m);
        if (ln == 0) {
            for (int r = 0; r < 4; ++r) redS[wv_][r] = s[r];
        }
    }
    __syncthreads();
    float kmv[4], kc4[4];
    for (int r = 0; r < 4; ++r) {
        kmv[r] = (redS[0][r] + redS[1][r] + redS[2][r] + redS[3][r]) * (1.f / HWF);
        kc4[r] = kt[r] - kmv[r];
    }
    {   // var partials
        float s[4];
        for (int r = 0; r < 4; ++r) s[r] = kc4[r] * kc4[r];
        for (int m = 1; m < 64; m <<= 1)
            for (int r = 0; r < 4; ++r) s[r] += __shfl_xor(s[r], m);
        if (ln == 0) {
            for (int r = 0; r < 4; ++r) redS[wv_][4 + r] = s[r];
        }
    }
    __syncthreads();
    float kvv[4];
    for (int r = 0; r < 4; ++r)
        kvv[r] = (redS[0][4+r] + redS[1][4+r] + redS[2][4+r] + redS[3][4+r]) * (1.f / (HWF - 1));

    const int jt = j0 >> 5;                 // 32-j tile index
    for (int r = 0; r < 4; ++r) {
        const int ro = (j0 & 31) + r;       // j within tile
        // K blob: [jt][row ro (j), 32 rows][512B: chunk^(ro&7)][8 bf16]
        kblob[jt * 8192 + ro * 256 + (((t >> 3) ^ (ro & 7)) * 8) + (t & 7)] = f2bf(kc4[r]);
        // V blob: [jt][row c=t (feature)][64B: 4 chunks ^(c&3)][8 bf16 over j]
        vblob[jt * 8192 + t * 32 + (((ro >> 3) ^ (t & 3)) * 8) + (ro & 7)] = f2bf(vt[r]);
    }
    if (t < 4) {
        const int j = j0 + t;
        sblob[j]            = 2.f * kmv[t];            // sa
        sblob[1024 + j]     = kmv[t] * kmv[t] + C1v;   // sb
        sblob[2048 + j]     = kvv[t] + C2v;            // sc
    }
}

// ---------------------------------------------------------------------------
// attn: TM=128 rows/block, 4 waves, wave rg owns 32 token rows x all j x all c.
// 2 blocks/CU (LDS 78KB): the co-resident wave on each SIMD belongs to a
// DIFFERENT barrier domain, so DMA-drain / barrier / latency stalls of one
// block are covered by the other block's compute.
// Swapped-operand MFMA chain keeps P in registers (round-1 structure):
//   prologue  qD = MFMA(Wq, x)  -> lane=token; cvt_pk+permlane32_swap -> qA frags
//   QK        S  = MFMA(K, qA)  -> lane=token, regs=j; ssim+exp in-register
//   pack      cvt_pk pairs + permlane32_swap -> PV A-frags (no P LDS)
//   PV        O += MFMA(P, V) over 8 col-tiles; l = f32 per-lane accumulator
// Stats are loaded ONCE (12 KB SoA) and read as row-vector ds_read_b128.
// MFMA 32x32x16 layouts (HW-verified m74/m101):
//   A[m=lane&31][k=8*(lane>>5)+e], B[k=8*(lane>>5)+e][n=lane&31],
//   D col=lane&31, row=(reg&3)+8*(reg>>2)+4*(lane>>5).
// ---------------------------------------------------------------------------
__global__ __launch_bounds__(THREADS, 2) void attn(
    const float* __restrict__ x, const short* __restrict__ wq_bf,
    const short* __restrict__ kblob, const short* __restrict__ vblob,
    const float* __restrict__ sblob, float* __restrict__ out)
{
    __shared__ __align__(16) char smem[SMEM_SZ];
    const int t = threadIdx.x, wave = t >> 6, lane = t & 63;
    const int lo = lane & 31, hi = lane >> 5;
    const int rg = wave;                    // 4 row-groups of 32 tokens
    const int n0 = blockIdx.x * TM;
    const int tok = n0 + 32 * rg + lo;      // this lane's token row

    // ---- DMA tile 0 + one-shot stats immediately (overlaps whole prologue) ----
    dma_tile16(kblob, smem, KB0, wave, lane);
    dma_tile16(vblob, smem, VB0, wave, lane);
    #pragma unroll
    for (int r = 0; r < 3; ++r) {           // 12 KB stats: 3 rounds x 4 waves x 1 KB
        __builtin_amdgcn_global_load_lds(
            (const __attribute__((address_space(1))) unsigned int*)
                ((const char*)sblob + r * 4096 + wave * 1024 + lane * 16),
            (__attribute__((address_space(3))) unsigned int*)
                (smem + STATS + r * 4096 + wave * 1024 + lane * 16), 16, 0, 0);
    }

    // ---- x B-frags: lane = token (n index), regs = feature ----
    bf16x8 xB[16];
    {
        const float* xr = x + (size_t)tok * HWF;
        #pragma unroll
        for (int s = 0; s < 16; ++s) {
            const float4 a = *reinterpret_cast<const float4*>(xr + 16 * s + 8 * hi);
            const float4 b = *reinterpret_cast<const float4*>(xr + 16 * s + 8 * hi + 4);
            uint4v u;
            u[0] = cvtpk(a.x, a.y); u[1] = cvtpk(a.z, a.w);
            u[2] = cvtpk(b.x, b.y); u[3] = cvtpk(b.z, b.w);
            xB[s] = __builtin_bit_cast(bf16x8, u);
        }
    }

    // ---- q = Wq @ x^T (swapped): D col = token, row = out-feature ----
    f32x16 qD[8];
    #pragma unroll
    for (int nt = 0; nt < 8; ++nt) qD[nt] = (f32x16)(0.f);
    #pragma unroll
    for (int nt = 0; nt < 8; ++nt) {
        #pragma unroll
        for (int s = 0; s < 16; ++s) {
            const bf16x8 wa = *reinterpret_cast<const bf16x8*>(
                wq_bf + (size_t)(32 * nt + lo) * HWF + 16 * s + 8 * hi);
            qD[nt] = MFMA32(wa, xB[s], qD[nt]);
        }
    }

    // ---- per-token stats fully in-lane (own half + partner half) ----
    float qs = 0.f, qss = 0.f;
    #pragma unroll
    for (int nt = 0; nt < 8; ++nt)
        #pragma unroll
        for (int i = 0; i < 16; ++i) {
            const float v = qD[nt][i];
            qs += v; qss = __builtin_fmaf(v, v, qss);
        }
    qs += __shfl_xor(qs, 32);
    qss += __shfl_xor(qss, 32);
    const float qm  = qs * (1.f / HWF);
    const float qv  = (qss - qs * qs * (1.f / HWF)) * (1.f / (HWF - 1));
    const float qm2 = qm * qm;

    // ---- qA frags in-register: cvt_pk pairs + permlane32_swap ----
    bf16x8 qA[16];
    #pragma unroll
    for (int nt = 0; nt < 8; ++nt) {
        unsigned w[8];
        #pragma unroll
        for (int p = 0; p < 8; ++p) w[p] = cvtpk(qD[nt][2 * p], qD[nt][2 * p + 1]);
        #pragma unroll
        for (int h = 0; h < 2; ++h) {
            unsigned a0 = w[4 * h + 0], b0 = w[4 * h + 2];
            unsigned a1 = w[4 * h + 1], b1 = w[4 * h + 3];
            plswap(a0, b0); plswap(a1, b1);
            uint4v u; u[0] = a0; u[1] = a1; u[2] = b0; u[3] = b1;
            qA[2 * nt + h] = __builtin_bit_cast(bf16x8, u);
        }
    }

    // ---- main loop over 32 j-tiles ----
    f32x16 O4[8];
    #pragma unroll
    for (int ct = 0; ct < 8; ++ct) O4[ct] = (f32x16)(0.f);
    float l = 0.f;
    const int rx = (lo & 7);                // K xor-swizzle nibble

    for (int jt = 0; jt < NT; ++jt) {
        const int cur = jt & 1;
        const int kb = cur ? KB1 : KB0, vb = cur ? VB1 : VB0;
        const int kbn = cur ? KB0 : KB1, vbn = cur ? VB0 : VB1;
        __syncthreads();                    // drains DMA(jt); prev tile reads done
        if (jt + 1 < NT) {                  // prefetch stays in flight across compute
            dma_tile16(kblob + (size_t)(jt + 1) * 8192, smem, kbn, wave, lane);
            dma_tile16(vblob + (size_t)(jt + 1) * 8192, smem, vbn, wave, lane);
        }

        // ---- S = K @ q^T : lane = token, regs = j-offset (32 j) ----
        f32x16 sacc = (f32x16)(0.f);
        __builtin_amdgcn_s_setprio(1);
        #pragma unroll
        for (int s = 0; s < 16; ++s) {
            const bf16x8 kfr = *reinterpret_cast<const bf16x8*>(
                smem + kb + lo * 512 + (((2 * s + hi) ^ rx) * 16));
            sacc = MFMA32(kfr, qA[s], sacc);
        }
        __builtin_amdgcn_s_setprio(0);

        // ---- ssim -> p -> packed bf16 pairs (stats via row-vector reads) ----
        unsigned pw[8];
        #pragma unroll
        for (int g = 0; g < 4; ++g) {
            const int soff = (32 * jt + 8 * g + 4 * hi) * 4;
            const f32x4 a4 = *reinterpret_cast<const f32x4*>(smem + STATS + soff);
            const f32x4 b4 = *reinterpret_cast<const f32x4*>(smem + STATS + 4096 + soff);
            const f32x4 c4 = *reinterpret_cast<const f32x4*>(smem + STATS + 8192 + soff);
            float pr[4];
            #pragma unroll
            for (int q = 0; q < 4; ++q) {
                const int i = 4 * g + q;
                const float cov2 = __builtin_fmaf(sacc[i], 2.f * RK, C2v);
                const float num  = __builtin_fmaf(a4[q], qm, C1v) * cov2;
                const float den  = __builtin_fmaf(qm2 + b4[q], qv + c4[q], EPSv);
                pr[q] = __expf(__fdividef(num, den));
                l += pr[q];
            }
            pw[2 * g]     = cvtpk(pr[0], pr[1]);
            pw[2 * g + 1] = cvtpk(pr[2], pr[3]);
        }

        // ---- O += P @ V : A-frags via permlane32_swap, B from LDS ----
        #pragma unroll
        for (int h = 0; h < 2; ++h) {
            unsigned a0 = pw[4 * h + 0], b0 = pw[4 * h + 2];
            unsigned a1 = pw[4 * h + 1], b1 = pw[4 * h + 3];
            plswap(a0, b0); plswap(a1, b1);
            uint4v u; u[0] = a0; u[1] = a1; u[2] = b0; u[3] = b1;
            const bf16x8 pa = __builtin_bit_cast(bf16x8, u);
            __builtin_amdgcn_s_setprio(1);
            #pragma unroll
            for (int ct = 0; ct < 8; ++ct) {
                const bf16x8 vfr = *reinterpret_cast<const bf16x8*>(
                    smem + vb + (32 * ct + lo) * 64 + (((2 * h + hi) ^ (lo & 3)) * 16));
                O4[ct] = MFMA32(pa, vfr, O4[ct]);
            }
            __builtin_amdgcn_s_setprio(0);
        }
    }

    // ---- l: lane-sum -> per-row via tiny wave-local LDS redistribute ----
    const float lf = l + __shfl_xor(l, 32);
    if (hi == 0)
        *reinterpret_cast<float*>(smem + LRED + (wave * 32 + lo) * 4) = lf;
    // same-wave DS ops complete in order; reads below see the writes
    float rl[16];
    #pragma unroll
    for (int g = 0; g < 4; ++g) {
        const f32x4 lv = *reinterpret_cast<const f32x4*>(
            smem + LRED + wave * 128 + (8 * g + 4 * hi) * 4);
        rl[4 * g + 0] = 1.f / lv[0];
        rl[4 * g + 1] = 1.f / lv[1];
        rl[4 * g + 2] = 1.f / lv[2];
        rl[4 * g + 3] = 1.f / lv[3];
    }

    #pragma unroll
    for (int ct = 0; ct < 8; ++ct) {
        #pragma unroll
        for (int i = 0; i < 16; ++i) {
            const int row = 32 * rg + (i & 3) + 8 * (i >> 2) + 4 * hi;
            out[(size_t)(n0 + row) * HWF + 32 * ct + lo] = O4[ct][i] * rl[i];
        }
    }
}

extern "C" void kernel_launch(void* const* d_in, const int* in_sizes, int n_in,
                              void* d_out, int out_size, void* d_ws, size_t ws_size,
                              hipStream_t stream) {
    (void)in_sizes; (void)n_in; (void)out_size; (void)ws_size;
    const float* x   = (const float*)d_in[0];
    const float* mem = (const float*)d_in[1];
    const float* Wq  = (const float*)d_in[2];
    const float* Wk  = (const float*)d_in[3];
    const float* Wv  = (const float*)d_in[4];
    float* out = (float*)d_out;

    // workspace (~1.2 MB): wq_bf | kblob | vblob | sblob (SoA: sa|sb|sc)
    short* wq_bf = (short*)d_ws;                        // 65536
    short* kblob = wq_bf + 65536;                       // 262144 (32 tiles x 8192)
    short* vblob = kblob + (size_t)MEMD * HWF;          // 262144
    float* sblob = (float*)(vblob + (size_t)MEMD * HWF);  // 3072 floats

    cast_wq<<<256, 256, 0, stream>>>(Wq, wq_bf);
    prep_kv<<<MEMD / 4, 256, 0, stream>>>(mem, Wk, Wv, kblob, vblob, sblob);
    attn<<<NROWS / TM, THREADS, 0, stream>>>(x, wq_bf, kblob, vblob, sblob, out);
}